// Round 1
// baseline (1149.628 us; speedup 1.0000x reference)
//
#include <hip/hip_runtime.h>

#define Bq 2
#define Sq 2048
#define Hq 1024
#define NHq 16
#define HDq 64

typedef __bf16 bf16x8 __attribute__((ext_vector_type(8)));
typedef float f32x4 __attribute__((ext_vector_type(4)));

__device__ __forceinline__ unsigned short f2b(float f) {
  union { float f; unsigned int u; } v; v.f = f;
  unsigned int u = v.u;
  u += 0x7fffu + ((u >> 16) & 1);   // RNE to bf16
  return (unsigned short)(u >> 16);
}

__global__ __launch_bounds__(256) void k_f2bf(const float* __restrict__ in,
                                              unsigned short* __restrict__ out, int n4) {
  int i = blockIdx.x * 256 + threadIdx.x;
  if (i >= n4) return;
  float4 v = ((const float4*)in)[i];
  ushort4 o;
  o.x = f2b(v.x); o.y = f2b(v.y); o.z = f2b(v.z); o.w = f2b(v.w);
  ((ushort4*)out)[i] = o;
}

// C[m][n] = sum_k A[m*lda+k] * B[n*ldb+k]   (both operands K-major, bf16)
// MODE 0: bf16 out -> [B,NH,S,HD] (+bias)     (Q,K projections)
// MODE 1: bf16 out -> [B,NH,HD,S] (+bias)     (V projection, transposed)
// MODE 2: fp32 out -> scores: mask ? v*0.125 : -1e9, z-strided (QK^T)
// MODE 3: fp32 out -> row-major [.,1024] + bias (out projection)
template<int MODE>
__global__ __launch_bounds__(256) void k_gemm_bt(
    const unsigned short* __restrict__ Abase,
    const unsigned short* __restrict__ Bbase,
    const float* __restrict__ bias,
    void* __restrict__ Cout,
    const int* __restrict__ mask,
    int Klen, int lda, int ldb,
    long sAz, long sBz, long sCz)
{
  __shared__ __align__(16) unsigned short As[128 * 32];
  __shared__ __align__(16) unsigned short Bs[128 * 32];

  const int tid = threadIdx.x;
  const int l = tid & 63;
  const int w = tid >> 6;
  const int z = blockIdx.z;
  const unsigned short* A  = Abase + (size_t)z * sAz;
  const unsigned short* Bm = Bbase + (size_t)z * sBz;
  const int row0 = blockIdx.y * 128;
  const int col0 = blockIdx.x * 128;

  const int wm = w & 1, wn = w >> 1;
  const int lrow = l & 15;
  const int lk = (l >> 4) * 8;

  f32x4 acc[4][4] = {};

  for (int kk = 0; kk < Klen; kk += 32) {
    __syncthreads();
#pragma unroll
    for (int c2 = 0; c2 < 2; ++c2) {
      int c = 2 * w + c2;
      int f = c * 512 + l * 8;
      int r = f >> 5, k = f & 31;
      __builtin_amdgcn_global_load_lds(
          (__attribute__((address_space(1))) void*)(A + (size_t)(row0 + r) * lda + kk + k),
          (__attribute__((address_space(3))) void*)(&As[c * 512]), 16, 0, 0);
      __builtin_amdgcn_global_load_lds(
          (__attribute__((address_space(1))) void*)(Bm + (size_t)(col0 + r) * ldb + kk + k),
          (__attribute__((address_space(3))) void*)(&Bs[c * 512]), 16, 0, 0);
    }
    __syncthreads();

    bf16x8 af[4], bfr[4];
#pragma unroll
    for (int mt = 0; mt < 4; ++mt)
      af[mt] = *(const bf16x8*)&As[(wm * 64 + mt * 16 + lrow) * 32 + lk];
#pragma unroll
    for (int nt = 0; nt < 4; ++nt)
      bfr[nt] = *(const bf16x8*)&Bs[(wn * 64 + nt * 16 + lrow) * 32 + lk];
#pragma unroll
    for (int mt = 0; mt < 4; ++mt)
#pragma unroll
      for (int nt = 0; nt < 4; ++nt)
        acc[mt][nt] = __builtin_amdgcn_mfma_f32_16x16x32_bf16(af[mt], bfr[nt], acc[mt][nt], 0, 0, 0);
  }

  const int quad = l >> 4;
#pragma unroll
  for (int mt = 0; mt < 4; ++mt) {
#pragma unroll
    for (int nt = 0; nt < 4; ++nt) {
#pragma unroll
      for (int r = 0; r < 4; ++r) {
        int grow = row0 + wm * 64 + mt * 16 + quad * 4 + r;
        int gcol = col0 + wn * 64 + nt * 16 + lrow;
        float v = acc[mt][nt][r];
        if constexpr (MODE == 0) {
          v += bias[gcol];
          int b = grow >> 11, s = grow & 2047;
          int nh = gcol >> 6, hd = gcol & 63;
          ((unsigned short*)Cout)[((size_t)(b * NHq + nh) * Sq + s) * HDq + hd] = f2b(v);
        } else if constexpr (MODE == 1) {
          v += bias[gcol];
          int b = grow >> 11, s = grow & 2047;
          int nh = gcol >> 6, hd = gcol & 63;
          ((unsigned short*)Cout)[((size_t)(b * NHq + nh) * HDq + hd) * Sq + s] = f2b(v);
        } else if constexpr (MODE == 2) {
          int b = z >> 4;
          int m = mask[(size_t)b * Sq * Sq + (size_t)grow * Sq + gcol];
          float sv = m ? v * 0.125f : -1e9f;
          ((float*)Cout)[(size_t)z * sCz + (size_t)grow * Sq + gcol] = sv;
        } else {
          ((float*)Cout)[(size_t)grow * Hq + gcol] = v + bias[gcol];
        }
      }
    }
  }
}

__global__ __launch_bounds__(256) void k_softmax(float* __restrict__ attn) {
  const size_t row = blockIdx.x;
  float* p = attn + row * (size_t)Sq;
  const int tid = threadIdx.x;
  float4 v0 = ((float4*)p)[tid * 2];
  float4 v1 = ((float4*)p)[tid * 2 + 1];
  float lmax = fmaxf(fmaxf(fmaxf(v0.x, v0.y), fmaxf(v0.z, v0.w)),
                     fmaxf(fmaxf(v1.x, v1.y), fmaxf(v1.z, v1.w)));
  __shared__ float red[256];
  red[tid] = lmax;
  __syncthreads();
  for (int s = 128; s > 0; s >>= 1) {
    if (tid < s) red[tid] = fmaxf(red[tid], red[tid + s]);
    __syncthreads();
  }
  float rmax = red[0];
  __syncthreads();
  float e0 = __expf(v0.x - rmax), e1 = __expf(v0.y - rmax);
  float e2 = __expf(v0.z - rmax), e3 = __expf(v0.w - rmax);
  float e4 = __expf(v1.x - rmax), e5 = __expf(v1.y - rmax);
  float e6 = __expf(v1.z - rmax), e7 = __expf(v1.w - rmax);
  float lsum = ((e0 + e1) + (e2 + e3)) + ((e4 + e5) + (e6 + e7));
  red[tid] = lsum;
  __syncthreads();
  for (int s = 128; s > 0; s >>= 1) {
    if (tid < s) red[tid] += red[tid + s];
    __syncthreads();
  }
  float inv = 1.0f / red[0];
  v0.x = e0 * inv; v0.y = e1 * inv; v0.z = e2 * inv; v0.w = e3 * inv;
  v1.x = e4 * inv; v1.y = e5 * inv; v1.z = e6 * inv; v1.w = e7 * inv;
  ((float4*)p)[tid * 2] = v0;
  ((float4*)p)[tid * 2 + 1] = v1;
}

// context[s][hd] = sum_j P[s][j] * V[j][hd], per head z. P fp32 (d_out), Vt bf16 [z][hd][s].
__global__ __launch_bounds__(256) void k_pv(
    const float* __restrict__ P,
    const unsigned short* __restrict__ Vt,
    unsigned short* __restrict__ ctx)
{
  __shared__ __align__(16) unsigned short Ps[128 * 64];
  __shared__ __align__(16) unsigned short Vs[64 * 64];
  const int tid = threadIdx.x;
  const int l = tid & 63, w = tid >> 6;
  const int z = blockIdx.z;
  const int i0 = blockIdx.y * 128;
  const float* Pz = P + (size_t)z * Sq * Sq;
  const unsigned short* Vz = Vt + (size_t)z * HDq * Sq;
  const int wm = w & 1, wn = w >> 1;
  const int lrow = l & 15;

  f32x4 acc[4][2] = {};

  const int rbase = tid >> 4;        // 0..15
  const int cbase = (tid & 15) * 4;  // 0..60

  for (int j0 = 0; j0 < Sq; j0 += 64) {
    __syncthreads();
    // stage P strip 128x64 fp32 -> bf16 LDS
#pragma unroll
    for (int p8 = 0; p8 < 8; ++p8) {
      int r = p8 * 16 + rbase;
      float4 pv = *(const float4*)&Pz[(size_t)(i0 + r) * Sq + j0 + cbase];
      ushort4 o;
      o.x = f2b(pv.x); o.y = f2b(pv.y); o.z = f2b(pv.z); o.w = f2b(pv.w);
      *(ushort4*)&Ps[r * 64 + cbase] = o;
    }
    // stage Vt strip 64x64 bf16 via global_load_lds
#pragma unroll
    for (int c2 = 0; c2 < 2; ++c2) {
      int c = 2 * w + c2;
      int f = c * 512 + l * 8;
      int n = f >> 6, k = f & 63;
      __builtin_amdgcn_global_load_lds(
          (__attribute__((address_space(1))) void*)(Vz + (size_t)n * Sq + j0 + k),
          (__attribute__((address_space(3))) void*)(&Vs[c * 512]), 16, 0, 0);
    }
    __syncthreads();
#pragma unroll
    for (int kq = 0; kq < 2; ++kq) {
      int k = kq * 32 + (l >> 4) * 8;
      bf16x8 af[4], bfr[2];
#pragma unroll
      for (int mt = 0; mt < 4; ++mt)
        af[mt] = *(const bf16x8*)&Ps[(wm * 64 + mt * 16 + lrow) * 64 + k];
#pragma unroll
      for (int nt = 0; nt < 2; ++nt)
        bfr[nt] = *(const bf16x8*)&Vs[(wn * 32 + nt * 16 + lrow) * 64 + k];
#pragma unroll
      for (int mt = 0; mt < 4; ++mt)
#pragma unroll
        for (int nt = 0; nt < 2; ++nt)
          acc[mt][nt] = __builtin_amdgcn_mfma_f32_16x16x32_bf16(af[mt], bfr[nt], acc[mt][nt], 0, 0, 0);
    }
  }

  const int quad = l >> 4;
  const int b = z >> 4, nh = z & 15;
#pragma unroll
  for (int mt = 0; mt < 4; ++mt)
#pragma unroll
    for (int nt = 0; nt < 2; ++nt)
#pragma unroll
      for (int r = 0; r < 4; ++r) {
        int srow = i0 + wm * 64 + mt * 16 + quad * 4 + r;
        int hd = wn * 32 + nt * 16 + lrow;
        ctx[((size_t)(b * Sq + srow)) * Hq + nh * HDq + hd] = f2b(acc[mt][nt][r]);
      }
}

extern "C" void kernel_launch(void* const* d_in, const int* in_sizes, int n_in,
                              void* d_out, int out_size, void* d_ws, size_t ws_size,
                              hipStream_t stream) {
  const float* query = (const float*)d_in[0];
  const float* key_  = (const float*)d_in[1];
  const float* value = (const float*)d_in[2];
  const int*   mask  = (const int*)d_in[3];
  const float* Wq = (const float*)d_in[4];
  const float* bq = (const float*)d_in[5];
  const float* Wk = (const float*)d_in[6];
  const float* bk = (const float*)d_in[7];
  const float* Wv = (const float*)d_in[8];
  const float* bv = (const float*)d_in[9];
  const float* Wo = (const float*)d_in[10];
  const float* bo = (const float*)d_in[11];

  unsigned short* Xq  = (unsigned short*)d_ws;           // 4096*1024
  unsigned short* Xk  = Xq  + (size_t)4096 * 1024;
  unsigned short* Xv  = Xk  + (size_t)4096 * 1024;
  unsigned short* Wqb = Xv  + (size_t)4096 * 1024;       // 1024*1024 each
  unsigned short* Wkb = Wqb + (size_t)1024 * 1024;
  unsigned short* Wvb = Wkb + (size_t)1024 * 1024;
  unsigned short* Wob = Wvb + (size_t)1024 * 1024;
  unsigned short* Qh  = Wob + (size_t)1024 * 1024;       // [32][2048][64]
  unsigned short* Kh  = Qh  + (size_t)32 * 2048 * 64;
  unsigned short* Vt  = Kh  + (size_t)32 * 2048 * 64;    // [32][64][2048]
  unsigned short* ctx = Vt  + (size_t)32 * 2048 * 64;    // [4096][1024]

  float* outp = (float*)d_out;                           // [4096][1024]
  float* attn = outp + (size_t)4096 * 1024;              // [32][2048][2048]

  // fp32 -> bf16 conversions
  k_f2bf<<<4096, 256, 0, stream>>>(query, Xq, 1048576);
  k_f2bf<<<4096, 256, 0, stream>>>(key_,  Xk, 1048576);
  k_f2bf<<<4096, 256, 0, stream>>>(value, Xv, 1048576);
  k_f2bf<<<1024, 256, 0, stream>>>(Wq, Wqb, 262144);
  k_f2bf<<<1024, 256, 0, stream>>>(Wk, Wkb, 262144);
  k_f2bf<<<1024, 256, 0, stream>>>(Wv, Wvb, 262144);
  k_f2bf<<<1024, 256, 0, stream>>>(Wo, Wob, 262144);

  // projections: [4096x1024] = X @ W^T + b
  dim3 gproj(8, 32, 1);
  k_gemm_bt<0><<<gproj, 256, 0, stream>>>(Xq, Wqb, bq, Qh, nullptr, 1024, 1024, 1024, 0, 0, 0);
  k_gemm_bt<0><<<gproj, 256, 0, stream>>>(Xk, Wkb, bk, Kh, nullptr, 1024, 1024, 1024, 0, 0, 0);
  k_gemm_bt<1><<<gproj, 256, 0, stream>>>(Xv, Wvb, bv, Vt, nullptr, 1024, 1024, 1024, 0, 0, 0);

  // scores = mask(Q K^T / 8): per head z, [2048x2048], K=64
  dim3 gqk(16, 16, 32);
  k_gemm_bt<2><<<gqk, 256, 0, stream>>>(Qh, Kh, nullptr, attn, mask, 64, 64, 64,
                                        131072, 131072, 4194304);

  // in-place row softmax on attn (also the final attn_weights output)
  k_softmax<<<65536, 256, 0, stream>>>(attn);

  // context = P @ V  (bf16 ctx in [B,S,H] layout)
  dim3 gpv(1, 16, 32);
  k_pv<<<gpv, 256, 0, stream>>>(attn, Vt, ctx);

  // output = ctx @ Wo^T + bo  (fp32 into d_out)
  dim3 gout(8, 32, 1);
  k_gemm_bt<3><<<gout, 256, 0, stream>>>(ctx, Wob, bo, outp, nullptr, 1024, 1024, 1024, 0, 0, 0);
}